// Round 7
// baseline (696.190 us; speedup 1.0000x reference)
//
#include <hip/hip_runtime.h>
#include <math.h>

// Observer recurrence -> LTI Markov-parameter convolution.
//   A' = A - L*C, K = [B - L*D | L | h0], f_m = C A'^m K
//   y_t = f_t[9] + D*u_t + sum_j f_j . z_{t-1-j};  out = 3*tanh(y)
// Round-15: fuse the R-chain INTO the V-blocks. r6 post-mortem: step time =
// request bytes / 6.4 TB/s; A' was read twice per step (32 MB V-role +
// 32 MB R-role) = 64 of ~80 MB. The R-partial for tile t needs exactly the
// fragments the V-block already holds in registers:
//   part[col] = sum_mr g[16t+mr] * A'[16t+mr][col]
// computed per fragment with 8 muls + 4-round __shfl_xor butterfly over the
// 16-lane mr-group (lanes q*16..q*16+15), lanes mr<8 write one col each.
// Each block also reduces the 256-partial x 16-col slice for its rows at
// step start (16 KB) and emits g_r. A' is now read ONCE per step:
// requests/step ~92 -> ~60 MB. Math unchanged (fp32 g carry, fp16 A).
// MITM split (28 V-apps + 27 R-apps), JT=56, dead-col skip as r12-r14.

constexpr int NDIM  = 4096;
constexpr int NC    = 10;         // live columns of K/W
constexpr int SLAB  = 16 * 4096;  // padded 16-col col-major slab (elements)
constexpr int JT    = 56;         // truncation length
constexpr int VAPPS = 28;         // V-chain applications (W_1..W_28)
constexpr int KC    = NDIM / 32;  // 128 k-chunks of 32
constexpr int TILES = NDIM / 16;  // 256 row-tiles of 16

typedef float    f32x4  __attribute__((ext_vector_type(4)));
typedef _Float16 h16x8  __attribute__((ext_vector_type(8)));
typedef _Float16 f16;

// ---------- build A' = A - L*C, fp16, swizzled to fragment order ----------
// AhSw element (h16x8): idx = (tile*KC + kc)*64 + lane
//   lane = mr + 16q holds A'[tile*16+mr][kc*32 + q*8 .. +7]
// LDS-staged: A read coalesced (256B segments), frags emitted from LDS.
__global__ __launch_bounds__(256) void k_build_a(
        const float* __restrict__ A, const float* __restrict__ C,
        const float* __restrict__ L, h16x8* __restrict__ AhSw) {
    __shared__ float lds[64][65];
    const int R0 = (blockIdx.x & 63) * 64;   // row-block
    const int C0 = (blockIdx.x >> 6) * 64;   // col-block
    const int tid = threadIdx.x;
    #pragma unroll
    for (int it = 0; it < 16; ++it) {
        const int r = it * 4 + (tid >> 6);
        const int c = tid & 63;
        lds[r][c] = A[(size_t)(R0 + r) * NDIM + C0 + c]
                  - L[R0 + r] * C[C0 + c];
    }
    __syncthreads();
    #pragma unroll
    for (int half = 0; half < 2; ++half) {
        const int o = half * 256 + tid;      // 0..511
        const int r = o >> 3;                // 0..63
        const int g = o & 7;                 // 8-col group
        union { h16x8 v; f16 h[8]; } pk;
        #pragma unroll
        for (int j = 0; j < 8; ++j) pk.h[j] = (f16)lds[r][g * 8 + j];
        const int tile = (R0 >> 4) + (r >> 4);
        const int kc   = (C0 >> 5) + (g >> 2);
        const int lane = (r & 15) | ((g & 3) << 4);
        AhSw[((size_t)tile * KC + kc) * 64 + lane] = pk.v;
    }
}

// ---------- W0 = K = [B-L*D | L | ones | 0-pad], fp32 + fp16 ----------
__global__ __launch_bounds__(256) void k_build_w0(
        const float* __restrict__ Bm, const float* __restrict__ Dm,
        const float* __restrict__ L,
        float* __restrict__ Wf, f16* __restrict__ Wh) {
    int k = blockIdx.x * blockDim.x + threadIdx.x; // < 4096
    float Lk = L[k];
    float col[16];
    #pragma unroll
    for (int c = 0; c < 8; ++c) col[c] = Bm[k * 8 + c] - Lk * Dm[c];
    col[8] = Lk; col[9] = 1.0f;
    #pragma unroll
    for (int c = 10; c < 16; ++c) col[c] = 0.0f;
    #pragma unroll
    for (int c = 0; c < 16; ++c) {
        Wf[c * NDIM + k] = col[c];
        Wh[c * NDIM + k] = (f16)col[c];
    }
}

// ---------- fused step: 256 blocks, block t owns tile t for BOTH chains ----
// phase 1: g_r slice (rows 16t..16t+16) = reduce 256 partials (or C at r=0)
// phase 2: V: W_{m+1} tile via MFMA (4 waves, k-split 4x1024, dead-col skip)
//          R: partials for g_{r+1} from the SAME ra registers (butterfly)
__global__ __launch_bounds__(256) void k_step(
        const h16x8* __restrict__ AhSw, const f16* __restrict__ WhIn,
        float* __restrict__ WfOut, f16* __restrict__ WhOut,
        const float* __restrict__ Cvec,
        const float* __restrict__ RpartIn, float* __restrict__ RpartOut,
        float* __restrict__ gfSlot, const int r) {
    __shared__ f32x4 red[4][64];
    __shared__ float rp[256][17];
    __shared__ float g16[16][17];
    __shared__ float gs[16];
    const int tid  = threadIdx.x;
    const int lane = tid & 63, wave = tid >> 6;
    const int mr   = lane & 15, q = lane >> 4;
    const int tile = blockIdx.x;
    const int row0 = tile * 16;
    const int k0   = wave * 1024;

    // ---- phase 1: g_r slice for rows [16t, 16t+16) ----
    if (r == 0) {
        if (tid < 16) gs[tid] = Cvec[row0 + tid];
    } else {
        const float* src = RpartIn + (size_t)tid * NDIM + row0;
        #pragma unroll
        for (int j = 0; j < 16; j += 4) {
            float4 v = *(const float4*)(src + j);
            rp[tid][j] = v.x; rp[tid][j+1] = v.y;
            rp[tid][j+2] = v.z; rp[tid][j+3] = v.w;
        }
        __syncthreads();
        {
            const int c = tid & 15, g = tid >> 4;   // 16 groups x 16 cols
            float s = 0.0f;
            #pragma unroll
            for (int j = 0; j < 16; ++j) s += rp[g * 16 + j][c];
            g16[g][c] = s;
        }
        __syncthreads();
        if (tid < 16) {
            float s = 0.0f;
            #pragma unroll
            for (int g = 0; g < 16; ++g) s += g16[g][tid];
            gs[tid] = s;
        }
    }
    __syncthreads();
    if (tid < 16) gfSlot[row0 + tid] = gs[tid];
    const float gmr = gs[mr];
    const bool doR = (r < VAPPS - 1);

    // ---- phase 2: V MFMA + R partials from shared ra registers ----
    const bool liveB = (mr < NC);
    const h16x8* a8 = AhSw + ((size_t)tile * KC + wave * 32) * 64 + lane;
    const h16x8* b8 = (const h16x8*)WhIn + (((size_t)mr * NDIM + k0) >> 3) + q;
    float* rpo = RpartOut + (size_t)tile * NDIM;

    f32x4 acc0 = {0,0,0,0}, acc1 = {0,0,0,0};
    for (int it = 0; it < 4; ++it) {
        h16x8 ra[8], rb[8];
        #pragma unroll
        for (int s = 0; s < 8; ++s) rb[s] = (h16x8){0,0,0,0,0,0,0,0};
        #pragma unroll
        for (int s = 0; s < 8; ++s) {
            const int c = it * 8 + s;           // kc-local 0..31
            ra[s] = a8[(size_t)c * 64];
        }
        if (liveB) {
            #pragma unroll
            for (int s = 0; s < 8; ++s) {
                const int c = it * 8 + s;
                rb[s] = b8[c * 4];
            }
        }
        #pragma unroll
        for (int s = 0; s < 8; ++s) {
            if (s & 1) acc1 = __builtin_amdgcn_mfma_f32_16x16x32_f16(ra[s], rb[s], acc1, 0, 0, 0);
            else       acc0 = __builtin_amdgcn_mfma_f32_16x16x32_f16(ra[s], rb[s], acc0, 0, 0, 0);
        }
        if (doR) {
            #pragma unroll
            for (int s = 0; s < 8; ++s) {
                union { h16x8 v; f16 h[8]; } ua;
                ua.v = ra[s];
                float p[8];
                #pragma unroll
                for (int j = 0; j < 8; ++j) p[j] = gmr * (float)ua.h[j];
                #pragma unroll
                for (int off = 1; off < 16; off <<= 1) {
                    #pragma unroll
                    for (int j = 0; j < 8; ++j)
                        p[j] += __shfl_xor(p[j], off, 16);
                }
                // lane mr (<8) writes col kcG*32 + q*8 + mr, value p[mr]
                const float s01 = (mr & 1) ? p[1] : p[0];
                const float s23 = (mr & 1) ? p[3] : p[2];
                const float s45 = (mr & 1) ? p[5] : p[4];
                const float s67 = (mr & 1) ? p[7] : p[6];
                const float s03 = (mr & 2) ? s23 : s01;
                const float s47 = (mr & 2) ? s67 : s45;
                const float sel = (mr & 4) ? s47 : s03;
                if (mr < 8) {
                    const int kcG = wave * 32 + it * 8 + s;
                    rpo[kcG * 32 + q * 8 + mr] = sel;
                }
            }
        }
    }
    red[wave][lane] = acc0 + acc1;
    __syncthreads();
    if (tid < 64) {
        f32x4 v = red[0][tid] + red[1][tid] + red[2][tid] + red[3][tid];
        const int col = tid & 15;
        if (col < NC) {
            const int rb0 = row0 + ((tid >> 4) << 2);
            #pragma unroll
            for (int i = 0; i < 4; ++i) {
                WfOut[col * NDIM + rb0 + i] = v[i];
                WhOut[col * NDIM + rb0 + i] = (f16)v[i];
            }
        }
    }
}

// ---------- f_m for all m: m<=28 via C.W_m, m=28+i via g_i.W_28 ----------
__global__ __launch_bounds__(256) void k_fbatch(
        const float* __restrict__ Wall, const float* __restrict__ C,
        const float* __restrict__ gf, float* __restrict__ F) {
    const int m = blockIdx.x;             // 0..JT-1
    const float* W;
    const float* vec;
    if (m <= VAPPS) { W = Wall + (size_t)m * SLAB;     vec = C; }
    else            { W = Wall + (size_t)VAPPS * SLAB; vec = gf + (size_t)(m - VAPPS) * NDIM; }
    const int tid = threadIdx.x, lane = tid & 63, wave = tid >> 6;
    float acc[NC] = {};
    for (int k = tid; k < NDIM; k += 256) {
        float ck = vec[k];
        #pragma unroll
        for (int c = 0; c < NC; ++c) acc[c] += ck * W[c * NDIM + k];
    }
    __shared__ float red[4][NC];
    #pragma unroll
    for (int c = 0; c < NC; ++c) {
        float s = acc[c];
        #pragma unroll
        for (int off = 32; off > 0; off >>= 1) s += __shfl_down(s, off);
        if (lane == 0) red[wave][c] = s;
    }
    __syncthreads();
    if (tid < NC) F[m * NC + tid] = red[0][tid] + red[1][tid] + red[2][tid] + red[3][tid];
}

// ---------- causal convolution + tanh epilogue ----------
__global__ __launch_bounds__(256) void k_conv(
        const float* __restrict__ F, const float* __restrict__ u,
        const float* __restrict__ yobs, const float* __restrict__ Dm,
        float* __restrict__ out) {
    __shared__ float Fl[JT * NC];
    __shared__ float zw[(JT + 256) * 9];
    const int tid = threadIdx.x;
    const int t0  = blockIdx.x * 256;
    for (int idx = tid; idx < JT * NC; idx += 256) Fl[idx] = F[idx];
    for (int idx = tid; idx < (JT + 256) * 9; idx += 256) {
        int k = idx / 9, c = idx - k * 9;
        int s = t0 - JT + k;
        float v = 0.0f;
        if (s >= 0 && s < NDIM) v = (c < 8) ? u[c * NDIM + s] : yobs[s];
        zw[idx] = v;
    }
    __syncthreads();
    const int t = t0 + tid;
    float y = (t < JT) ? Fl[t * NC + 9] : 0.0f; // C A'^t h0 term (truncated)
    #pragma unroll
    for (int c = 0; c < 8; ++c) y += Dm[c] * u[c * NDIM + t];
    for (int j = 0; j < JT; ++j) { // s = t-1-j; s<0 hits zero pad
        const float* fj = Fl + j * NC;
        const float* zz = zw + (tid + JT - 1 - j) * 9;
        float p = 0.0f;
        #pragma unroll
        for (int c = 0; c < 9; ++c) p += fj[c] * zz[c];
        y += p;
    }
    out[t] = 3.0f * tanhf(y);
}

extern "C" void kernel_launch(void* const* d_in, const int* in_sizes, int n_in,
                              void* d_out, int out_size, void* d_ws, size_t ws_size,
                              hipStream_t stream) {
    const float* u    = (const float*)d_in[0];
    const float* yobs = (const float*)d_in[1];
    const float* A    = (const float*)d_in[2];
    const float* Bm   = (const float*)d_in[3];
    const float* C    = (const float*)d_in[4];
    const float* Dm   = (const float*)d_in[5];
    const float* L    = (const float*)d_in[6];
    float* out = (float*)d_out;

    // workspace layout (~54 MB)
    char* ws = (char*)d_ws;
    h16x8* AhSw  = (h16x8*)ws;                        // 32 MB
    float* Wf    = (float*)(ws + 33554432ull);        // 29*256 KB
    f16*   Wh    = (f16*)(ws + 41156608ull);          // 29*128 KB
    float* gf    = (float*)(ws + 44957696ull);        // 28*16 KB
    float* Rpart = (float*)(ws + 45416448ull);        // 2 * 4 MB (ping-pong)
    float* F     = (float*)(ws + 53805056ull);        // 2.24 KB

    constexpr size_t RPN = (size_t)256 * NDIM;        // one Rpart buffer (elems)

    k_build_a<<<dim3(64 * 64), dim3(256), 0, stream>>>(A, C, L, AhSw);
    k_build_w0<<<dim3(16), dim3(256), 0, stream>>>(Bm, Dm, L, Wf, Wh);

    for (int r = 0; r < VAPPS; ++r) {
        const size_t in   = (size_t)r * SLAB;
        const size_t out_ = (size_t)(r + 1) * SLAB;
        const float* rin  = Rpart + ((r + 1) & 1) * RPN;
        float*       rout = Rpart + (r & 1) * RPN;
        k_step<<<dim3(256), dim3(256), 0, stream>>>(
            AhSw, Wh + in, Wf + out_, Wh + out_,
            C, rin, rout, gf + (size_t)r * NDIM, r);
    }

    k_fbatch<<<dim3(JT), dim3(256), 0, stream>>>(Wf, C, gf, F);
    k_conv<<<dim3(16), dim3(256), 0, stream>>>(F, u, yobs, Dm, out);
}